// Round 1
// baseline (250.649 us; speedup 1.0000x reference)
//
#include <hip/hip_runtime.h>
#include <hip/hip_fp16.h>

#define DIM 128
#define EPS 1e-5f
#define WPB 8            // waves per block (512 threads)
#define EPT 16           // edges per NODE per trip (8 per quarter, 2 nodes/wave)

// native clang ext-vectors (needed for __builtin_nontemporal_store)
typedef float vfloat4 __attribute__((ext_vector_type(4)));

// ---------------------------------------------------------------------------
// Prep kernel (fused): convert x fp32 -> fp16; build CSR row_ptr from the
// sorted edge_row (thread e covers rows (row[e-1], row[e]]).
// ---------------------------------------------------------------------------
__global__ void prep_kernel(const float4* __restrict__ x4,
                            __half2* __restrict__ xh2,
                            const int* __restrict__ edge_row,
                            int* __restrict__ row_ptr,
                            int n4, int n_nodes, int n_edges)
{
    int i = blockIdx.x * blockDim.x + threadIdx.x;
    if (i < n4) {
        float4 v = x4[i];
        xh2[2 * i]     = __float22half2_rn(make_float2(v.x, v.y));
        xh2[2 * i + 1] = __float22half2_rn(make_float2(v.z, v.w));
    }
    if (i < n_edges) {
        int cur  = edge_row[i];
        int prev = (i == 0) ? -1 : edge_row[i - 1];
        for (int r = prev + 1; r <= cur; ++r) row_ptr[r] = i;
        if (i == n_edges - 1) {
            for (int r = cur + 1; r <= n_nodes; ++r) row_ptr[r] = n_edges;
        }
    }
}

// ---------------------------------------------------------------------------
// One trip = 16 edges of one node, processed by a 32-lane half-wave.
//   q   = (lane>>4)&1 : owns 8 consecutive edges (base e0 + 8q)
//   sub = lane&15     : dim group [sub*8, sub*8+8), gathered as 16B
// MASKED trips (head/tail) clamp the edge-vector loads into the array and
// zero w for out-of-row edges. c is NOT masked: any loaded edge_col entry is
// a valid node id, so the gather is safe and w=0 kills the contribution.
// Interior trips are provably fully in-row: no clamp, no masks.
// ---------------------------------------------------------------------------
template<bool MASKED>
__device__ __forceinline__
void edge_trip(int e0, int q, int sub, int start, unsigned len, int emax,
               const uint4* __restrict__ xh16,
               const int*   __restrict__ edge_col,
               const float* __restrict__ edge_val,
               float acc[8])
{
    const int b = e0 + 8 * q;                  // this quarter's 8 edges
    int b0 = b, b1 = b + 4;
    if (MASKED) { b0 = min(b0, emax); b1 = min(b1, emax); }

    int4   c4a = *(const int4*)  (edge_col + b0);
    int4   c4b = *(const int4*)  (edge_col + b1);
    float4 w4a = *(const float4*)(edge_val + b0);
    float4 w4b = *(const float4*)(edge_val + b1);

    int   c[8] = {c4a.x, c4a.y, c4a.z, c4a.w, c4b.x, c4b.y, c4b.z, c4b.w};
    float w[8] = {w4a.x, w4a.y, w4a.z, w4a.w, w4b.x, w4b.y, w4b.z, w4b.w};

    if (MASKED) {
        const int off = b - start;             // may be <0 at head (q=0)
#pragma unroll
        for (int u = 0; u < 8; ++u)
            w[u] = ((unsigned)(off + u) < len) ? w[u] : 0.f;
    }

    uint4 v[8];                                 // 8 gathers in flight
#pragma unroll
    for (int u = 0; u < 8; ++u)
        v[u] = xh16[c[u] * (DIM / 8) + sub];   // 16B/lane; 4 rows/instr

#pragma unroll
    for (int u = 0; u < 8; ++u) {
        const __half* hp = (const __half*)&v[u];
#pragma unroll
        for (int j = 0; j < 8; ++j)            // fp16 operand -> v_fma_mix
            acc[j] = fmaf(w[u], __half2float(hp[j]), acc[j]);
    }
}

// ---------------------------------------------------------------------------
// Main kernel: TWO nodes per wave (one per 32-lane half). Doubles per-wave
// outstanding gathers (8 instrs in flight), halves per-node epilogue cost
// and wave count vs the 1-node/wave version.
// ---------------------------------------------------------------------------
__global__ __launch_bounds__(WPB * 64)
void gnn_fused_kernel(const uint4* __restrict__ xh16,   // fp16 x, 16B units
                      const int*   __restrict__ row_ptr,
                      const int*   __restrict__ edge_col,
                      const float* __restrict__ edge_val,
                      const float* __restrict__ gamma,
                      const float* __restrict__ beta,
                      float*       __restrict__ out,
                      int n_nodes, int n_edges)
{
    const int wave = threadIdx.x >> 6;
    const int lane = threadIdx.x & 63;
    const int q    = (lane >> 4) & 1;          // quarter within half-wave
    const int sub  = lane & 15;                // dim group
    const int node = (blockIdx.x * WPB + wave) * 2 + (lane >> 5);
    if (node >= n_nodes) return;               // half-wave-uniform branch;
                                               // all shuffles stay in-half

    const int start = row_ptr[node];
    const int end   = row_ptr[node + 1];
    const unsigned len = (unsigned)(end - start);

    // residual row: issue early, latency hides under the edge loop
    const uint4 xv = xh16[node * (DIM / 8) + sub];

    float acc[8];
#pragma unroll
    for (int k = 0; k < 8; ++k) acc[k] = 0.f;

    const int emax  = n_edges - 4;
    const int ebase = start & ~3;              // 16B-align edge vec loads
    int e0 = ebase;
    if (e0 < end) {                            // head trip (masked)
        edge_trip<true>(e0, q, sub, start, len, emax,
                        xh16, edge_col, edge_val, acc);
        e0 += EPT;
    }
    while (e0 + EPT <= end) {                  // interior trips (mask-free)
        edge_trip<false>(e0, q, sub, start, len, emax,
                         xh16, edge_col, edge_val, acc);
        e0 += EPT;
    }
    if (e0 < end) {                            // tail trip (masked)
        edge_trip<true>(e0, q, sub, start, len, emax,
                        xh16, edge_col, edge_val, acc);
    }

    // fold the two quarters of this node's half-wave (disjoint edge subsets)
#pragma unroll
    for (int k = 0; k < 8; ++k)
        acc[k] += __shfl_xor(acc[k], 16, 64);

    // residual from fp16 x
    const __half* xp = (const __half*)&xv;
    float h[8];
#pragma unroll
    for (int j = 0; j < 8; ++j) h[j] = acc[j] + __half2float(xp[j]);

    // layernorm stats: per-lane over 8 dims, butterfly over sub (1,2,4,8)
    float s = 0.f, sq = 0.f;
#pragma unroll
    for (int k = 0; k < 8; ++k) { s += h[k]; sq += h[k] * h[k]; }
#pragma unroll
    for (int off = 1; off <= 8; off <<= 1) {
        s  += __shfl_xor(s,  off, 64);
        sq += __shfl_xor(sq, off, 64);
    }
    const float mean = s * (1.0f / (float)DIM);
    const float var  = sq * (1.0f / (float)DIM) - mean * mean;
    const float rs   = rsqrtf(var + EPS);

    // lane (q,sub) writes dims sub*8 + q*4 + {0..3}: 512B contiguous / node
    float h0 = q ? h[4] : h[0];
    float h1 = q ? h[5] : h[1];
    float h2 = q ? h[6] : h[2];
    float h3 = q ? h[7] : h[3];
    const int didx = sub * 2 + q;              // float4 index within row
    const float4 gm = ((const float4*)gamma)[didx];
    const float4 bt = ((const float4*)beta)[didx];
    vfloat4 o;
    o.x = (h0 - mean) * rs * gm.x + bt.x;
    o.y = (h1 - mean) * rs * gm.y + bt.y;
    o.z = (h2 - mean) * rs * gm.z + bt.z;
    o.w = (h3 - mean) * rs * gm.w + bt.w;
    __builtin_nontemporal_store(o, (vfloat4*)out + node * (DIM / 4) + didx);
}

extern "C" void kernel_launch(void* const* d_in, const int* in_sizes, int n_in,
                              void* d_out, int out_size, void* d_ws, size_t ws_size,
                              hipStream_t stream)
{
    const float* x        = (const float*)d_in[0];
    const int*   edge_row = (const int*)  d_in[1];
    const int*   edge_col = (const int*)  d_in[2];
    const float* edge_val = (const float*)d_in[3];
    const float* gamma    = (const float*)d_in[4];
    const float* beta     = (const float*)d_in[5];
    float*       out      = (float*)d_out;

    const int n_nodes = in_sizes[0] / DIM;   // 100000
    const int n_edges = in_sizes[1];         // 3200000
    const int n_elem  = in_sizes[0];         // N*DIM
    const int n4      = n_elem / 4;

    // workspace: [x_half: n_elem*2 B][row_ptr: (n_nodes+1)*4 B]
    __half2* xh2     = (__half2*)d_ws;
    int*     row_ptr = (int*)((char*)d_ws + (size_t)n_elem * sizeof(__half));

    int prep_threads = (n4 > n_edges) ? n4 : n_edges;
    prep_kernel<<<(prep_threads + 255) / 256, 256, 0, stream>>>(
        (const float4*)x, xh2, edge_row, row_ptr, n4, n_nodes, n_edges);

    const int nodes_per_block = WPB * 2;
    const int blocks = (n_nodes + nodes_per_block - 1) / nodes_per_block;
    gnn_fused_kernel<<<blocks, WPB * 64, 0, stream>>>(
        (const uint4*)d_ws, row_ptr, edge_col, edge_val, gamma, beta, out,
        n_nodes, n_edges);
}